// Round 2
// baseline (657.887 us; speedup 1.0000x reference)
//
#include <hip/hip_runtime.h>

#define N_NODES 50000
#define N_EDGES 640000
#define D 128               // D_IN == D_OUT == 128
#define NBINS 392           // bin = dst>>7 (128 nodes/bin); 392*128 = 50176 >= N
#define NCHUNK 96           // fat edge chunks for hist/scatter
#define EPC 6667            // 96*6667 = 640032 >= E
#define BINCAP 2048         // slots/bin: mean 1638, sigma 40 -> +10 sigma safe

// ---------------------------------------------------------------------------
// 5-dispatch, ZERO-global-atomic pipeline (replaces 640K device-scope ticket
// atomics measured at ~5.2 RMW/cycle = 51us wall in the old fused kernel):
//  D1 hist:    96 blocks x 6667 edges -> LDS hist over 392 bins (LDS atomics
//              only), coalesced hist[chunk][bin] store. wcvt fused (blk 0,1).
//  D2 scan:    per-bin exclusive scan of 96 chunk counts + per-bin totals.
//  D3 scatter: re-read edges, LDS ticket per (chunk,bin), write 4B record
//              (dst16|src16) at bin*2048+base+rank. Runs of ~17 recs = 68B
//              contiguous -> kills the 35MB write-allocate bloat.
//  D4 gemm:    Y = feat @ W in bf16 MFMA (verified tile, edge code removed).
//  D5 gather:  1 block per 64-node half-bin; 32KB LDS f32 acc; streams the
//              bin's now-CONTIGUOUS records; per edge one wave reads Y[src]
//              (64 lanes x u32) and ds_add_f32s into acc (interleaved col
//              layout -> 2-way bank alias = free). + bias, write out.
// Workspace: Y bf16 12.8MB | Wf 32KB | hist 147KB | base 147KB | total 1.5KB
//            | recs 3.1MB  (~16.3MB total, fits prior 19.4MB ws).
// ---------------------------------------------------------------------------

typedef __attribute__((ext_vector_type(8))) short short8;   // 8 bf16 (4 VGPRs)
typedef __attribute__((ext_vector_type(4))) float f32x4;    // MFMA C/D

static __device__ inline unsigned pkbf(float lo, float hi) {
    unsigned a = __float_as_uint(lo) + 0x8000u;
    unsigned b = __float_as_uint(hi) + 0x8000u;
    return __builtin_amdgcn_perm(b, a, 0x07060302);
}
static __device__ inline unsigned short f2bf(float f) {
    return (unsigned short)((__float_as_uint(f) + 0x8000u) >> 16);
}
static __device__ inline float bflo(unsigned u) { return __uint_as_float(u << 16); }
static __device__ inline float bfhi(unsigned u) { return __uint_as_float(u & 0xFFFF0000u); }

// D1: per-chunk histogram over bins (LDS atomics only) + fused wcvt.
// wcvt: W f32 row-major -> Wf bf16 B-fragments; entry e=((kt*8+nt)*16+n)*4+q
// holds B[k=kt*32+q*8+j][c=nt*16+n], j=0..7.
__global__ __launch_bounds__(1024) void hist_kernel(
        const int* __restrict__ dst,
        const float* __restrict__ W,
        uint4* __restrict__ Wf,
        unsigned* __restrict__ hist) {
    __shared__ unsigned h[NBINS];
    const int t = threadIdx.x;
    const int blk = blockIdx.x;
    if (t < NBINS) h[t] = 0;

    if (blk < 2) {                                   // fused wcvt: e = 0..2047
        int e = blk * 1024 + t;
        int q  = e & 3;
        int n  = (e >> 2) & 15;
        int nt = (e >> 6) & 7;
        int kt = e >> 9;
        const float* p = W + (kt * 32 + q * 8) * D + nt * 16 + n;
        unsigned u[8];
        #pragma unroll
        for (int j = 0; j < 8; ++j) u[j] = __float_as_uint(p[j * D]) + 0x8000u;
        uint4 o;
        o.x = __builtin_amdgcn_perm(u[1], u[0], 0x07060302);
        o.y = __builtin_amdgcn_perm(u[3], u[2], 0x07060302);
        o.z = __builtin_amdgcn_perm(u[5], u[4], 0x07060302);
        o.w = __builtin_amdgcn_perm(u[7], u[6], 0x07060302);
        Wf[e] = o;
    }
    __syncthreads();

    const int start = blk * EPC;
    const int end = min(start + EPC, N_EDGES);
    for (int e = start + t; e < end; e += 1024)
        atomicAdd(&h[((unsigned)dst[e]) >> 7], 1u);  // LDS atomic
    __syncthreads();
    if (t < NBINS) hist[blk * NBINS + t] = h[t];     // coalesced
}

// D2: per-bin exclusive scan across the 96 chunks (coalesced across bins).
__global__ __launch_bounds__(512) void scan_kernel(
        const unsigned* __restrict__ hist,
        unsigned* __restrict__ base,
        unsigned* __restrict__ total) {
    int b = threadIdx.x;
    if (b >= NBINS) return;
    unsigned run = 0;
    for (int k = 0; k < NCHUNK; ++k) {
        unsigned u = hist[k * NBINS + b];
        base[k * NBINS + b] = run;
        run += u;
    }
    total[b] = run;
}

// D3: scatter edges into per-bin contiguous record arrays. LDS tickets only.
__global__ __launch_bounds__(1024) void scatter_kernel(
        const int* __restrict__ src,
        const int* __restrict__ dst,
        const unsigned* __restrict__ base,
        unsigned* __restrict__ recs) {
    __shared__ unsigned h[NBINS];
    __shared__ unsigned lb[NBINS];
    const int t = threadIdx.x;
    const int blk = blockIdx.x;
    if (t < NBINS) { h[t] = 0; lb[t] = base[blk * NBINS + t]; }
    __syncthreads();
    const int start = blk * EPC;
    const int end = min(start + EPC, N_EDGES);
    for (int e = start + t; e < end; e += 1024) {
        int d = dst[e];
        int s = src[e];
        unsigned bin = ((unsigned)d) >> 7;
        unsigned r = atomicAdd(&h[bin], 1u);         // LDS ticket
        unsigned off = lb[bin] + r;
        if (off < BINCAP)                            // impossible; OOB guard
            recs[bin * BINCAP + off] = (((unsigned)d) << 16) | (unsigned)s;
    }
}

// D4: pure gemm tile (16 rows/block). A-frag: lane(n,q) holds A[m=n][k=q*8+j];
// C/D: col=n, row=q*4+reg. B-frags: 8 coalesced uint4/lane from Wf.
__global__ __launch_bounds__(256) void gemm_kernel(
        const uint4* __restrict__ Wf,
        const float* __restrict__ feat,
        unsigned short* __restrict__ Y) {
    const int t = threadIdx.x;
    const int tile = blockIdx.x;                     // 0..3124
    const int wave = t >> 6;
    const int lane = t & 63;
    const int n = lane & 15;
    const int q = lane >> 4;

    short8 bfrag[4][2];
    #pragma unroll
    for (int kt = 0; kt < 4; ++kt) {
        #pragma unroll
        for (int p = 0; p < 2; ++p) {
            int nt = wave * 2 + p;
            uint4 raw = Wf[(((kt * 8 + nt) * 16 + n) << 2) + q];
            bfrag[kt][p] = *(const short8*)&raw;
        }
    }

    const float* ap = feat + (size_t)(tile * 16 + n) * D + q * 8;
    f32x4 acc0 = {0.f, 0.f, 0.f, 0.f};
    f32x4 acc1 = {0.f, 0.f, 0.f, 0.f};
    #pragma unroll
    for (int kt = 0; kt < 4; ++kt) {
        float4 f0 = *(const float4*)(ap + kt * 32);
        float4 f1 = *(const float4*)(ap + kt * 32 + 4);
        int4 pa;
        pa.x = (int)pkbf(f0.x, f0.y);
        pa.y = (int)pkbf(f0.z, f0.w);
        pa.z = (int)pkbf(f1.x, f1.y);
        pa.w = (int)pkbf(f1.z, f1.w);
        short8 afrag = *(const short8*)&pa;
        acc0 = __builtin_amdgcn_mfma_f32_16x16x32_bf16(afrag, bfrag[kt][0], acc0, 0, 0, 0);
        acc1 = __builtin_amdgcn_mfma_f32_16x16x32_bf16(afrag, bfrag[kt][1], acc1, 0, 0, 0);
    }
    unsigned short* yp = Y + (size_t)(tile * 16 + q * 4) * D + n;
    #pragma unroll
    for (int i = 0; i < 4; ++i) {
        yp[(size_t)i * D + wave * 32]      = f2bf(acc0[i]);
        yp[(size_t)i * D + wave * 32 + 16] = f2bf(acc1[i]);
    }
}

// D5: gather. Block = one 64-node half-bin; acc in LDS f32 (interleaved cols:
// col c -> idx (c>>1) + (c&1)*64, so the u32-row-load's two bf16 halves land
// at lane and lane+64 -> 2-way bank alias = free). 4-deep edge unroll for MLP.
__global__ __launch_bounds__(256) void gather_kernel(
        const unsigned* __restrict__ recs,
        const unsigned* __restrict__ total,
        const unsigned* __restrict__ Yu,     // Y rows as 64 x u32
        const float4* __restrict__ b4,       // [32] float4
        float* __restrict__ out) {
    __shared__ float acc[64 * D];            // 32 KB
    const int t = threadIdx.x;
    const int bin = blockIdx.x >> 1;
    const unsigned half = blockIdx.x & 1;
    int cnt = (int)total[bin];
    if (cnt > BINCAP) cnt = BINCAP;          // bound reads even if bin overflow
    for (int i = t; i < 64 * D; i += 256) acc[i] = 0.f;
    __syncthreads();

    const int w = t >> 6;
    const int lane = t & 63;
    const unsigned* rb = recs + bin * BINCAP;

    for (int e = w; e < cnt; e += 16) {      // wave w handles e≡w (mod 4), 4-deep
        unsigned r[4]; bool q[4]; unsigned y[4];
        #pragma unroll
        for (int u = 0; u < 4; ++u) {
            int ee = e + 4 * u;
            bool v = (ee < cnt);
            r[u] = v ? rb[ee] : 0u;
            q[u] = v && (((r[u] >> 22) & 1u) == half);   // dst bit6 = half
            y[u] = 0u;
        }
        #pragma unroll
        for (int u = 0; u < 4; ++u)
            if (q[u]) y[u] = Yu[(size_t)(r[u] & 0xFFFFu) * 64 + lane];
        #pragma unroll
        for (int u = 0; u < 4; ++u)
            if (q[u]) {
                int ab = (int)((r[u] >> 16) & 63u) << 7;
                atomicAdd(&acc[ab + lane],      bflo(y[u]));   // ds_add_f32
                atomicAdd(&acc[ab + 64 + lane], bfhi(y[u]));
            }
    }
    __syncthreads();

    const int node0 = bin * 128 + (int)half * 64;
    #pragma unroll
    for (int i = 0; i < 8; ++i) {
        int idx = i * 256 + t;
        int rr = idx >> 5;                   // row within half-bin
        int c4 = idx & 31;                   // float4 column group
        int node = node0 + rr;
        if (node < N_NODES) {
            float4 bb = b4[c4];
            const float* ar = acc + rr * D;
            int hh = c4 * 2;
            float4 o;
            o.x = ar[hh]      + bb.x;        // col 4c4   -> idx 2c4
            o.y = ar[hh + 64] + bb.y;        // col 4c4+1 -> idx 2c4+64
            o.z = ar[hh + 1]  + bb.z;        // col 4c4+2 -> idx 2c4+1
            o.w = ar[hh + 65] + bb.w;        // col 4c4+3 -> idx 2c4+65
            *(float4*)(out + (size_t)node * D + c4 * 4) = o;
        }
    }
}

// ---------------------------------------------------------------------------
extern "C" void kernel_launch(void* const* d_in, const int* in_sizes, int n_in,
                              void* d_out, int out_size, void* d_ws, size_t ws_size,
                              hipStream_t stream) {
    const float* feat = (const float*)d_in[0];   // [50000,128] f32
    const int*   src  = (const int*)d_in[1];     // [640000] int32
    const int*   dst  = (const int*)d_in[2];     // [640000] int32
    const float* W    = (const float*)d_in[3];   // [128,128] f32
    const float* b    = (const float*)d_in[4];   // [1,128]   f32
    float* out = (float*)d_out;                  // [50000,128] f32

    unsigned short* Y = (unsigned short*)d_ws;                        // 12.8 MB
    uint4* Wf = (uint4*)((char*)d_ws + (size_t)N_NODES * D * 2);      // 32 KB
    unsigned* hist  = (unsigned*)((char*)Wf + 2048 * sizeof(uint4));  // 147 KB
    unsigned* base  = hist + NCHUNK * NBINS;                          // 147 KB
    unsigned* total = base + NCHUNK * NBINS;                          // 1.5 KB
    unsigned* recs  = total + NBINS;                                  // 3.1 MB

    hist_kernel<<<NCHUNK, 1024, 0, stream>>>(dst, W, Wf, hist);
    scan_kernel<<<1, 512, 0, stream>>>(hist, base, total);
    scatter_kernel<<<NCHUNK, 1024, 0, stream>>>(src, dst, base, recs);
    gemm_kernel<<<3125, 256, 0, stream>>>(Wf, feat, Y);
    gather_kernel<<<NBINS * 2, 256, 0, stream>>>(
        recs, total, (const unsigned*)Y, (const float4*)b, out);
}

// Round 3
// 157.029 us; speedup vs baseline: 4.1896x; 4.1896x over previous
//
#include <hip/hip_runtime.h>

#define N_NODES 50000
#define N_EDGES 640000
#define D 128               // D_IN == D_OUT == 128
#define NBINS 392           // bin = dst>>7 (128 nodes/bin); 392*128 = 50176 >= N
#define NCHUNK 96           // fat edge chunks for hist/scatter
#define EPC 6667            // 96*6667 = 640032 >= E

// ---------------------------------------------------------------------------
// 6-dispatch, zero-global-atomic pipeline. R2 lesson: the sort front-end is
// fine (hist/scan/scatter/gemm all left the top-5), but the half-bin gather
// (784 blocks = 12 waves/CU, 256B loads, LDS-atomic critical path) was pure
// unhidden latency: 547us @ VALUBusy 4%. Fix: make the sort produce an EXACT
// per-node CSR and run the round-0 PROVEN gather (1 wave/node = 50K waves,
// 1KB uint4 loads, register acc + shfl reduce, ~45us) on top of it.
//  D1 hist:     96 blocks, LDS hist over 392 bins (+ fused wcvt in blk 0,1).
//  D2 scan:     per-(chunk,bin) global offsets + bin prefix -> binbase[393].
//  D3 scatter:  LDS tickets -> recs[] = (dst16|src16), contiguous by bin.
//  D4 nodesort: 392 blocks; per-bin LDS count/scan/scatter over 128 nodes ->
//               exact CSR: nodeoff[50177], edst[] u16 src ids per node.
//  D5 gemm:     Y = feat @ W, bf16 MFMA (verified tile).
//  D6 gather:   round-0 gather, CSR-exact (no CAP=64 truncation), chunked
//               for deg>64. out[d] = sum Y[src] + b.
// Workspace: Y 12.8MB | Wf 32KB | hist 147KB | base 147KB | binbase 1.6KB |
//            nodeoff 200KB | recs 2.56MB | edst 1.28MB  (~17.2MB).
// ---------------------------------------------------------------------------

typedef __attribute__((ext_vector_type(8))) short short8;   // 8 bf16 (4 VGPRs)
typedef __attribute__((ext_vector_type(4))) float f32x4;    // MFMA C/D

static __device__ inline unsigned pkbf(float lo, float hi) {
    unsigned a = __float_as_uint(lo) + 0x8000u;
    unsigned b = __float_as_uint(hi) + 0x8000u;
    return __builtin_amdgcn_perm(b, a, 0x07060302);
}
static __device__ inline unsigned short f2bf(float f) {
    return (unsigned short)((__float_as_uint(f) + 0x8000u) >> 16);
}
static __device__ inline float bflo(unsigned u) { return __uint_as_float(u << 16); }
static __device__ inline float bfhi(unsigned u) { return __uint_as_float(u & 0xFFFF0000u); }

// D1: per-chunk histogram over bins (LDS atomics only) + fused wcvt.
__global__ __launch_bounds__(1024) void hist_kernel(
        const int* __restrict__ dst,
        const float* __restrict__ W,
        uint4* __restrict__ Wf,
        unsigned* __restrict__ hist) {
    __shared__ unsigned h[NBINS];
    const int t = threadIdx.x;
    const int blk = blockIdx.x;
    if (t < NBINS) h[t] = 0;

    if (blk < 2) {                                   // fused wcvt: e = 0..2047
        int e = blk * 1024 + t;
        int q  = e & 3;
        int n  = (e >> 2) & 15;
        int nt = (e >> 6) & 7;
        int kt = e >> 9;
        const float* p = W + (kt * 32 + q * 8) * D + nt * 16 + n;
        unsigned u[8];
        #pragma unroll
        for (int j = 0; j < 8; ++j) u[j] = __float_as_uint(p[j * D]) + 0x8000u;
        uint4 o;
        o.x = __builtin_amdgcn_perm(u[1], u[0], 0x07060302);
        o.y = __builtin_amdgcn_perm(u[3], u[2], 0x07060302);
        o.z = __builtin_amdgcn_perm(u[5], u[4], 0x07060302);
        o.w = __builtin_amdgcn_perm(u[7], u[6], 0x07060302);
        Wf[e] = o;
    }
    __syncthreads();

    const int start = blk * EPC;
    const int end = min(start + EPC, N_EDGES);
    for (int e = start + t; e < end; e += 1024)
        atomicAdd(&h[((unsigned)dst[e]) >> 7], 1u);  // LDS atomic
    __syncthreads();
    if (t < NBINS) hist[blk * NBINS + t] = h[t];     // coalesced
}

// D2: per-(chunk,bin) exclusive offsets made GLOBAL via bin prefix scan.
__global__ __launch_bounds__(512) void scan_kernel(
        const unsigned* __restrict__ hist,
        unsigned* __restrict__ base,
        unsigned* __restrict__ binbase) {
    __shared__ unsigned tot[NBINS];
    __shared__ unsigned bbs[NBINS + 1];
    const int b = threadIdx.x;
    if (b < NBINS) {
        unsigned s = 0;
        for (int k = 0; k < NCHUNK; ++k) s += hist[k * NBINS + b];
        tot[b] = s;
    }
    __syncthreads();
    if (b == 0) {
        unsigned a = 0;
        for (int i = 0; i < NBINS; ++i) { bbs[i] = a; a += tot[i]; }
        bbs[NBINS] = a;                              // == N_EDGES
    }
    __syncthreads();
    if (b <= NBINS) binbase[b] = bbs[b];
    if (b < NBINS) {
        unsigned run = bbs[b];
        for (int k = 0; k < NCHUNK; ++k) {
            base[k * NBINS + b] = run;
            run += hist[k * NBINS + b];
        }
    }
}

// D3: scatter edges into bin-contiguous record array. LDS tickets only.
__global__ __launch_bounds__(1024) void scatter_kernel(
        const int* __restrict__ src,
        const int* __restrict__ dst,
        const unsigned* __restrict__ base,
        unsigned* __restrict__ recs) {
    __shared__ unsigned h[NBINS];
    __shared__ unsigned lb[NBINS];
    const int t = threadIdx.x;
    const int blk = blockIdx.x;
    if (t < NBINS) { h[t] = 0; lb[t] = base[blk * NBINS + t]; }
    __syncthreads();
    const int start = blk * EPC;
    const int end = min(start + EPC, N_EDGES);
    for (int e = start + t; e < end; e += 1024) {
        int d = dst[e];
        int s = src[e];
        unsigned bin = ((unsigned)d) >> 7;
        unsigned r = atomicAdd(&h[bin], 1u);         // LDS ticket
        unsigned off = lb[bin] + r;
        if (off < N_EDGES)                           // exact; guard for safety
            recs[off] = (((unsigned)d) << 16) | (unsigned)s;
    }
}

// D4: per-bin node sort -> exact CSR. Block = bin: LDS count over 128 nodes,
// serial 128-scan, LDS-ticket scatter of src16 into edst[]. ~1633 recs/bin.
__global__ __launch_bounds__(256) void nodesort_kernel(
        const unsigned* __restrict__ recs,
        const unsigned* __restrict__ binbase,
        unsigned* __restrict__ nodeoff,
        unsigned short* __restrict__ edst) {
    __shared__ unsigned cnt128[128];
    __shared__ unsigned ns[129];
    __shared__ unsigned tick[128];
    const int t = threadIdx.x;
    const int b = blockIdx.x;
    const unsigned s0 = binbase[b];
    const unsigned e1 = binbase[b + 1];
    if (t < 128) cnt128[t] = 0;
    __syncthreads();
    for (unsigned i = s0 + t; i < e1; i += 256)
        atomicAdd(&cnt128[(recs[i] >> 16) & 127u], 1u);
    __syncthreads();
    if (t == 0) {
        unsigned a = 0;
        for (int i = 0; i < 128; ++i) { ns[i] = a; a += cnt128[i]; }
        ns[128] = a;
    }
    __syncthreads();
    if (t < 128) {
        tick[t] = ns[t];
        nodeoff[b * 128 + t] = s0 + ns[t];
    }
    if (b == 0 && t == 128) nodeoff[NBINS * 128] = N_EDGES;
    __syncthreads();
    for (unsigned i = s0 + t; i < e1; i += 256) {
        unsigned r = recs[i];
        unsigned off = s0 + atomicAdd(&tick[(r >> 16) & 127u], 1u);
        edst[off] = (unsigned short)(r & 0xFFFFu);
    }
}

// D5: pure gemm tile (16 rows/block). A-frag: lane(n,q) holds A[m=n][k=q*8+j];
// C/D: col=n, row=q*4+reg. B-frags: 8 coalesced uint4/lane from Wf.
__global__ __launch_bounds__(256) void gemm_kernel(
        const uint4* __restrict__ Wf,
        const float* __restrict__ feat,
        unsigned short* __restrict__ Y) {
    const int t = threadIdx.x;
    const int tile = blockIdx.x;                     // 0..3124
    const int wave = t >> 6;
    const int lane = t & 63;
    const int n = lane & 15;
    const int q = lane >> 4;

    short8 bfrag[4][2];
    #pragma unroll
    for (int kt = 0; kt < 4; ++kt) {
        #pragma unroll
        for (int p = 0; p < 2; ++p) {
            int nt = wave * 2 + p;
            uint4 raw = Wf[(((kt * 8 + nt) * 16 + n) << 2) + q];
            bfrag[kt][p] = *(const short8*)&raw;
        }
    }

    const float* ap = feat + (size_t)(tile * 16 + n) * D + q * 8;
    f32x4 acc0 = {0.f, 0.f, 0.f, 0.f};
    f32x4 acc1 = {0.f, 0.f, 0.f, 0.f};
    #pragma unroll
    for (int kt = 0; kt < 4; ++kt) {
        float4 f0 = *(const float4*)(ap + kt * 32);
        float4 f1 = *(const float4*)(ap + kt * 32 + 4);
        int4 pa;
        pa.x = (int)pkbf(f0.x, f0.y);
        pa.y = (int)pkbf(f0.z, f0.w);
        pa.z = (int)pkbf(f1.x, f1.y);
        pa.w = (int)pkbf(f1.z, f1.w);
        short8 afrag = *(const short8*)&pa;
        acc0 = __builtin_amdgcn_mfma_f32_16x16x32_bf16(afrag, bfrag[kt][0], acc0, 0, 0, 0);
        acc1 = __builtin_amdgcn_mfma_f32_16x16x32_bf16(afrag, bfrag[kt][1], acc1, 0, 0, 0);
    }
    unsigned short* yp = Y + (size_t)(tile * 16 + q * 4) * D + n;
    #pragma unroll
    for (int i = 0; i < 4; ++i) {
        yp[(size_t)i * D + wave * 32]      = f2bf(acc0[i]);
        yp[(size_t)i * D + wave * 32 + 16] = f2bf(acc1[i]);
    }
}

// D6: round-0 gather on exact CSR. One wave per node (50K waves: latency
// hidden by TLP). Lane (q=lane>>4, c=lane&15) owns cols [c*8,c*8+8) of row
// j+q; one uint4 wave-load covers 4 rows (1KB). Cross-quarter: shfl_xor.
__global__ __launch_bounds__(256) void gather_kernel(
        const uint4* __restrict__ Y4,        // [N][16] uint4 (row = 256B)
        const unsigned* __restrict__ nodeoff,
        const unsigned short* __restrict__ edst,
        const float4* __restrict__ b4,       // [32] float4
        float* __restrict__ out) {
    int node = (blockIdx.x * 256 + threadIdx.x) >> 6;
    int lane = threadIdx.x & 63;
    if (node >= N_NODES) return;
    unsigned start = nodeoff[node];
    int cnt = (int)(nodeoff[node + 1] - start);      // exact degree
    const int q = lane >> 4;
    const int c = lane & 15;

    float ax[8];
    #pragma unroll
    for (int i = 0; i < 8; ++i) ax[i] = 0.f;

    for (int c0 = 0; c0 < cnt; c0 += 64) {           // deg>64 handled exactly
        int m = min(cnt - c0, 64);
        int eid = (lane < m) ? (int)edst[start + c0 + lane] : 0;  // coalesced
        for (int j = 0; j < m; j += 4) {
            int idx = j + q;                         // this quarter's row slot
            int sid = __shfl(eid, idx & 63);         // wrap safe: masked below
            uint4 v = make_uint4(0u, 0u, 0u, 0u);
            if (idx < m) v = Y4[(size_t)sid * 16 + c];
            ax[0] += bflo(v.x); ax[1] += bfhi(v.x);
            ax[2] += bflo(v.y); ax[3] += bfhi(v.y);
            ax[4] += bflo(v.z); ax[5] += bfhi(v.z);
            ax[6] += bflo(v.w); ax[7] += bfhi(v.w);
        }
    }

    #pragma unroll
    for (int i = 0; i < 8; ++i) {
        ax[i] += __shfl_xor(ax[i], 16);
        ax[i] += __shfl_xor(ax[i], 32);              // all lanes hold full sums
    }

    if (lane < 32) {
        int q2 = lane >> 4;                          // 0: cols c*8+0..3, 1: +4..7
        float4 bb = b4[c * 2 + q2];
        float4 o;
        o.x = ax[q2 * 4 + 0] + bb.x;
        o.y = ax[q2 * 4 + 1] + bb.y;
        o.z = ax[q2 * 4 + 2] + bb.z;
        o.w = ax[q2 * 4 + 3] + bb.w;
        *(float4*)(out + (size_t)node * D + c * 8 + q2 * 4) = o;
    }
}

// ---------------------------------------------------------------------------
extern "C" void kernel_launch(void* const* d_in, const int* in_sizes, int n_in,
                              void* d_out, int out_size, void* d_ws, size_t ws_size,
                              hipStream_t stream) {
    const float* feat = (const float*)d_in[0];   // [50000,128] f32
    const int*   src  = (const int*)d_in[1];     // [640000] int32
    const int*   dst  = (const int*)d_in[2];     // [640000] int32
    const float* W    = (const float*)d_in[3];   // [128,128] f32
    const float* b    = (const float*)d_in[4];   // [1,128]   f32
    float* out = (float*)d_out;                  // [50000,128] f32

    unsigned short* Y = (unsigned short*)d_ws;                        // 12.8 MB
    uint4* Wf = (uint4*)((char*)d_ws + (size_t)N_NODES * D * 2);      // 32 KB
    unsigned* hist    = (unsigned*)((char*)Wf + 2048 * sizeof(uint4));// 147 KB
    unsigned* base    = hist + NCHUNK * NBINS;                        // 147 KB
    unsigned* binbase = base + NCHUNK * NBINS;                        // 1.6 KB
    unsigned* nodeoff = binbase + (NBINS + 1);                        // 200 KB
    unsigned* recs    = nodeoff + (NBINS * 128 + 1);                  // 2.56 MB
    unsigned short* edst = (unsigned short*)(recs + N_EDGES);         // 1.28 MB

    hist_kernel<<<NCHUNK, 1024, 0, stream>>>(dst, W, Wf, hist);
    scan_kernel<<<1, 512, 0, stream>>>(hist, base, binbase);
    scatter_kernel<<<NCHUNK, 1024, 0, stream>>>(src, dst, base, recs);
    nodesort_kernel<<<NBINS, 256, 0, stream>>>(recs, binbase, nodeoff, edst);
    gemm_kernel<<<3125, 256, 0, stream>>>(Wf, feat, Y);
    gather_kernel<<<N_NODES * 64 / 256, 256, 0, stream>>>(
        (const uint4*)Y, nodeoff, edst, (const float4*)b, out);
}

// Round 4
// 148.537 us; speedup vs baseline: 4.4291x; 1.0572x over previous
//
#include <hip/hip_runtime.h>

#define N_NODES 50000
#define N_EDGES 640000
#define D 128               // D_IN == D_OUT == 128
#define NBINS 392           // bin = dst>>7 (128 nodes/bin); 392*128 = 50176 >= N
#define NCHUNK 96           // fat edge chunks for hist/scatter
#define NQUADS 160000       // N_EDGES/4 (int4 granularity; 640000 % 4 == 0)
#define EPC4 1667           // int4 quads per chunk: 96*1667 = 160032 >= 160000

// ---------------------------------------------------------------------------
// 5-dispatch, zero-global-atomic pipeline. R3: all dispatches < 44us; time is
// fill(45, harness) + gather(~40) + sort(~30) + gemm(~15) + ~6 gaps(~20).
// R4 changes: (1) scan dispatch REMOVED - scatter/nodesort blocks recompute
// offsets from the L2-hot 150KB hist (Hillis-Steele over 392 bins in LDS,
// redundant-but-parallel); (2) int4 edge streams in hist/scatter; (3) gather
// main loop made guard-free (j+4<=m iterations provably in-bounds) with 2
// Y-row loads in flight -> breaks the exec-mask serialization per iteration.
//  D1 hist:     96 blocks, LDS hist over 392 bins (+ fused wcvt in blk 0,1).
//  D2 scatter:  self-scan -> global bases; LDS tickets -> recs=(dst16|src16).
//  D3 nodesort: 392 blocks, self-scan -> binbase; per-bin 128-node LDS sort
//               -> exact CSR (nodeoff[50177], edst u16 per node).
//  D4 gemm:     Y = feat @ W, bf16 MFMA (verified tile).
//  D5 gather:   1 wave/node on exact CSR, uint4 row loads, shfl reduce.
// Workspace: Y 12.8MB | Wf 32KB | hist 150KB | nodeoff 201KB | recs 2.56MB |
//            edst 1.28MB (~17MB).
// ---------------------------------------------------------------------------

typedef __attribute__((ext_vector_type(8))) short short8;   // 8 bf16 (4 VGPRs)
typedef __attribute__((ext_vector_type(4))) float f32x4;    // MFMA C/D

static __device__ inline unsigned pkbf(float lo, float hi) {
    unsigned a = __float_as_uint(lo) + 0x8000u;
    unsigned b = __float_as_uint(hi) + 0x8000u;
    return __builtin_amdgcn_perm(b, a, 0x07060302);
}
static __device__ inline unsigned short f2bf(float f) {
    return (unsigned short)((__float_as_uint(f) + 0x8000u) >> 16);
}
static __device__ inline float bflo(unsigned u) { return __uint_as_float(u << 16); }
static __device__ inline float bfhi(unsigned u) { return __uint_as_float(u & 0xFFFF0000u); }

// D1: per-chunk histogram over bins (LDS atomics, int4 edge stream) + wcvt.
__global__ __launch_bounds__(1024) void hist_kernel(
        const int4* __restrict__ dst4,
        const float* __restrict__ W,
        uint4* __restrict__ Wf,
        unsigned* __restrict__ hist) {
    __shared__ unsigned h[NBINS];
    const int t = threadIdx.x;
    const int blk = blockIdx.x;
    if (t < NBINS) h[t] = 0;

    if (blk < 2) {                                   // fused wcvt: e = 0..2047
        int e = blk * 1024 + t;
        int q  = e & 3;
        int n  = (e >> 2) & 15;
        int nt = (e >> 6) & 7;
        int kt = e >> 9;
        const float* p = W + (kt * 32 + q * 8) * D + nt * 16 + n;
        unsigned u[8];
        #pragma unroll
        for (int j = 0; j < 8; ++j) u[j] = __float_as_uint(p[j * D]) + 0x8000u;
        uint4 o;
        o.x = __builtin_amdgcn_perm(u[1], u[0], 0x07060302);
        o.y = __builtin_amdgcn_perm(u[3], u[2], 0x07060302);
        o.z = __builtin_amdgcn_perm(u[5], u[4], 0x07060302);
        o.w = __builtin_amdgcn_perm(u[7], u[6], 0x07060302);
        Wf[e] = o;
    }
    __syncthreads();

    const int i0 = blk * EPC4;
    const int i1 = min(i0 + EPC4, NQUADS);
    for (int i = i0 + t; i < i1; i += 1024) {
        int4 d = dst4[i];
        atomicAdd(&h[((unsigned)d.x) >> 7], 1u);
        atomicAdd(&h[((unsigned)d.y) >> 7], 1u);
        atomicAdd(&h[((unsigned)d.z) >> 7], 1u);
        atomicAdd(&h[((unsigned)d.w) >> 7], 1u);
    }
    __syncthreads();
    if (t < NBINS) hist[blk * NBINS + t] = h[t];     // coalesced
}

// D2: scatter with self-computed global bases (no scan dispatch).
__global__ __launch_bounds__(1024) void scatter_kernel(
        const int4* __restrict__ src4,
        const int4* __restrict__ dst4,
        const unsigned* __restrict__ hist,
        unsigned* __restrict__ recs) {
    __shared__ unsigned sc[512];
    __shared__ unsigned lb[NBINS];
    __shared__ unsigned h[NBINS];
    const int t = threadIdx.x;
    const int blk = blockIdx.x;

    unsigned pre = 0, tot = 0;                       // per-bin t: prefix & total
    if (t < NBINS)
        for (int k = 0; k < NCHUNK; ++k) {
            unsigned v = hist[k * NBINS + t];
            if (k < blk) pre += v;
            tot += v;
        }
    if (t < 512) sc[t] = (t < NBINS) ? tot : 0;
    __syncthreads();
    for (int off = 1; off < 512; off <<= 1) {        // inclusive scan over bins
        unsigned v = 0;
        if (t < 512) { v = sc[t]; if (t >= off) v += sc[t - off]; }
        __syncthreads();
        if (t < 512) sc[t] = v;
        __syncthreads();
    }
    if (t < NBINS) {
        unsigned bbs = (t == 0) ? 0u : sc[t - 1];    // exclusive bin base
        lb[t] = bbs + pre;                           // this block's write base
        h[t] = 0;
    }
    __syncthreads();

    const int i0 = blk * EPC4;
    const int i1 = min(i0 + EPC4, NQUADS);
    for (int i = i0 + t; i < i1; i += 1024) {
        int4 s = src4[i];
        int4 d = dst4[i];
        #pragma unroll
        for (int u = 0; u < 4; ++u) {
            int dd = (u == 0) ? d.x : (u == 1) ? d.y : (u == 2) ? d.z : d.w;
            int ss = (u == 0) ? s.x : (u == 1) ? s.y : (u == 2) ? s.z : s.w;
            unsigned bin = ((unsigned)dd) >> 7;
            unsigned r = atomicAdd(&h[bin], 1u);     // LDS ticket
            unsigned off = lb[bin] + r;
            if (off < N_EDGES)                       // exact; safety guard
                recs[off] = (((unsigned)dd) << 16) | (unsigned)ss;
        }
    }
}

// D3: per-bin node sort -> exact CSR; binbase self-computed from hist.
__global__ __launch_bounds__(512) void nodesort_kernel(
        const unsigned* __restrict__ hist,
        const unsigned* __restrict__ recs,
        unsigned* __restrict__ nodeoff,
        unsigned short* __restrict__ edst) {
    __shared__ unsigned sc[512];
    __shared__ unsigned cnt128[128];
    __shared__ unsigned ns[129];
    __shared__ unsigned tick[128];
    const int t = threadIdx.x;
    const int b = blockIdx.x;

    unsigned tot = 0;
    if (t < NBINS)
        for (int k = 0; k < NCHUNK; ++k) tot += hist[k * NBINS + t];
    sc[t] = (t < NBINS) ? tot : 0;
    __syncthreads();
    for (int off = 1; off < 512; off <<= 1) {
        unsigned v = sc[t];
        if (t >= off) v += sc[t - off];
        __syncthreads();
        sc[t] = v;
        __syncthreads();
    }
    const unsigned s0 = (b == 0) ? 0u : sc[b - 1];   // binbase[b] (broadcast)
    const unsigned e1 = sc[b];                       // binbase[b+1]

    if (t < 128) cnt128[t] = 0;
    __syncthreads();
    for (unsigned i = s0 + t; i < e1; i += 512)
        atomicAdd(&cnt128[(recs[i] >> 16) & 127u], 1u);
    __syncthreads();
    if (t == 0) {
        unsigned a = 0;
        for (int i = 0; i < 128; ++i) { ns[i] = a; a += cnt128[i]; }
        ns[128] = a;
    }
    __syncthreads();
    if (t < 128) {
        tick[t] = ns[t];
        nodeoff[b * 128 + t] = s0 + ns[t];
    }
    if (b == 0 && t == 128) nodeoff[NBINS * 128] = N_EDGES;
    __syncthreads();
    for (unsigned i = s0 + t; i < e1; i += 512) {
        unsigned r = recs[i];
        unsigned off = s0 + atomicAdd(&tick[(r >> 16) & 127u], 1u);
        edst[off] = (unsigned short)(r & 0xFFFFu);
    }
}

// D4: pure gemm tile (16 rows/block). A-frag: lane(n,q) holds A[m=n][k=q*8+j];
// C/D: col=n, row=q*4+reg. B-frags: 8 coalesced uint4/lane from Wf.
__global__ __launch_bounds__(256) void gemm_kernel(
        const uint4* __restrict__ Wf,
        const float* __restrict__ feat,
        unsigned short* __restrict__ Y) {
    const int t = threadIdx.x;
    const int tile = blockIdx.x;                     // 0..3124
    const int wave = t >> 6;
    const int lane = t & 63;
    const int n = lane & 15;
    const int q = lane >> 4;

    short8 bfrag[4][2];
    #pragma unroll
    for (int kt = 0; kt < 4; ++kt) {
        #pragma unroll
        for (int p = 0; p < 2; ++p) {
            int nt = wave * 2 + p;
            uint4 raw = Wf[(((kt * 8 + nt) * 16 + n) << 2) + q];
            bfrag[kt][p] = *(const short8*)&raw;
        }
    }

    const float* ap = feat + (size_t)(tile * 16 + n) * D + q * 8;
    f32x4 acc0 = {0.f, 0.f, 0.f, 0.f};
    f32x4 acc1 = {0.f, 0.f, 0.f, 0.f};
    #pragma unroll
    for (int kt = 0; kt < 4; ++kt) {
        float4 f0 = *(const float4*)(ap + kt * 32);
        float4 f1 = *(const float4*)(ap + kt * 32 + 4);
        int4 pa;
        pa.x = (int)pkbf(f0.x, f0.y);
        pa.y = (int)pkbf(f0.z, f0.w);
        pa.z = (int)pkbf(f1.x, f1.y);
        pa.w = (int)pkbf(f1.z, f1.w);
        short8 afrag = *(const short8*)&pa;
        acc0 = __builtin_amdgcn_mfma_f32_16x16x32_bf16(afrag, bfrag[kt][0], acc0, 0, 0, 0);
        acc1 = __builtin_amdgcn_mfma_f32_16x16x32_bf16(afrag, bfrag[kt][1], acc1, 0, 0, 0);
    }
    unsigned short* yp = Y + (size_t)(tile * 16 + q * 4) * D + n;
    #pragma unroll
    for (int i = 0; i < 4; ++i) {
        yp[(size_t)i * D + wave * 32]      = f2bf(acc0[i]);
        yp[(size_t)i * D + wave * 32 + 16] = f2bf(acc1[i]);
    }
}

#define ACC8(v)                                              \
    do {                                                     \
        ax[0] += bflo((v).x); ax[1] += bfhi((v).x);          \
        ax[2] += bflo((v).y); ax[3] += bfhi((v).y);          \
        ax[4] += bflo((v).z); ax[5] += bfhi((v).z);          \
        ax[6] += bflo((v).w); ax[7] += bfhi((v).w);          \
    } while (0)

// D5: gather on exact CSR. One wave per node (50K waves). Main loop is
// GUARD-FREE (j+8<=m => idx=j+q and j+4+q < m for all quarters) with two
// 1KB row-loads in flight; then one guard-free single; then masked tail.
__global__ __launch_bounds__(256) void gather_kernel(
        const uint4* __restrict__ Y4,        // [N][16] uint4 (row = 256B)
        const unsigned* __restrict__ nodeoff,
        const unsigned short* __restrict__ edst,
        const float4* __restrict__ b4,       // [32] float4
        float* __restrict__ out) {
    int node = (blockIdx.x * 256 + threadIdx.x) >> 6;
    int lane = threadIdx.x & 63;
    if (node >= N_NODES) return;
    unsigned start = nodeoff[node];
    int cnt = (int)(nodeoff[node + 1] - start);      // exact degree
    const int q = lane >> 4;
    const int c = lane & 15;

    float ax[8];
    #pragma unroll
    for (int i = 0; i < 8; ++i) ax[i] = 0.f;

    for (int c0 = 0; c0 < cnt; c0 += 64) {           // deg>64 handled exactly
        int m = min(cnt - c0, 64);
        int eid = (lane < m) ? (int)edst[start + c0 + lane] : 0;
        int j = 0;
        for (; j + 8 <= m; j += 8) {                 // 2 loads in flight
            int sA = __shfl(eid, j + q);
            int sB = __shfl(eid, j + 4 + q);
            uint4 vA = Y4[(size_t)sA * 16 + c];
            uint4 vB = Y4[(size_t)sB * 16 + c];
            ACC8(vA);
            ACC8(vB);
        }
        for (; j + 4 <= m; j += 4) {                 // guard-free single
            int s = __shfl(eid, j + q);
            uint4 v = Y4[(size_t)s * 16 + c];
            ACC8(v);
        }
        if (j < m) {                                 // masked tail (<=3 rows)
            int idx = j + q;
            int s = __shfl(eid, (idx < m) ? idx : 0);
            uint4 v = make_uint4(0u, 0u, 0u, 0u);
            if (idx < m) v = Y4[(size_t)s * 16 + c];
            ACC8(v);
        }
    }

    #pragma unroll
    for (int i = 0; i < 8; ++i) {
        ax[i] += __shfl_xor(ax[i], 16);
        ax[i] += __shfl_xor(ax[i], 32);              // all lanes hold full sums
    }

    if (lane < 32) {
        int q2 = lane >> 4;                          // 0: cols c*8+0..3, 1: +4..7
        float4 bb = b4[c * 2 + q2];
        float4 o;
        o.x = ax[q2 * 4 + 0] + bb.x;
        o.y = ax[q2 * 4 + 1] + bb.y;
        o.z = ax[q2 * 4 + 2] + bb.z;
        o.w = ax[q2 * 4 + 3] + bb.w;
        *(float4*)(out + (size_t)node * D + c * 8 + q2 * 4) = o;
    }
}

// ---------------------------------------------------------------------------
extern "C" void kernel_launch(void* const* d_in, const int* in_sizes, int n_in,
                              void* d_out, int out_size, void* d_ws, size_t ws_size,
                              hipStream_t stream) {
    const float* feat = (const float*)d_in[0];   // [50000,128] f32
    const int*   src  = (const int*)d_in[1];     // [640000] int32
    const int*   dst  = (const int*)d_in[2];     // [640000] int32
    const float* W    = (const float*)d_in[3];   // [128,128] f32
    const float* b    = (const float*)d_in[4];   // [1,128]   f32
    float* out = (float*)d_out;                  // [50000,128] f32

    unsigned short* Y = (unsigned short*)d_ws;                        // 12.8 MB
    uint4* Wf = (uint4*)((char*)d_ws + (size_t)N_NODES * D * 2);      // 32 KB
    unsigned* hist    = (unsigned*)((char*)Wf + 2048 * sizeof(uint4));// 150 KB
    unsigned* nodeoff = hist + NCHUNK * NBINS;                        // 201 KB
    unsigned* recs    = nodeoff + (NBINS * 128 + 1);                  // 2.56 MB
    unsigned short* edst = (unsigned short*)(recs + N_EDGES);         // 1.28 MB

    hist_kernel<<<NCHUNK, 1024, 0, stream>>>((const int4*)dst, W, Wf, hist);
    scatter_kernel<<<NCHUNK, 1024, 0, stream>>>(
        (const int4*)src, (const int4*)dst, hist, recs);
    nodesort_kernel<<<NBINS, 512, 0, stream>>>(hist, recs, nodeoff, edst);
    gemm_kernel<<<3125, 256, 0, stream>>>(Wf, feat, Y);
    gather_kernel<<<N_NODES * 64 / 256, 256, 0, stream>>>(
        (const uint4*)Y, nodeoff, edst, (const float4*)b, out);
}

// Round 6
// 146.732 us; speedup vs baseline: 4.4836x; 1.0123x over previous
//
#include <hip/hip_runtime.h>

#define N_NODES 50000
#define N_EDGES 640000
#define D 128               // D_IN == D_OUT == 128
#define NBINS 392           // bin = dst>>7 (128 nodes/bin); 392*128 = 50176 >= N
#define NCHUNK 96           // fat edge chunks for hist/scatter
#define NQUADS 160000       // N_EDGES/4 (int4 granularity; 640000 % 4 == 0)
#define EPC4 1667           // int4 quads per chunk: 96*1667 = 160032 >= 160000
#define BINCAP 2048         // LDS staging cap in nodesort (mean 1638, +10σ)

// ---------------------------------------------------------------------------
// 5-dispatch, zero-global-atomic pipeline. R5's scatter+gemm mega-fusion
// core-dumped; reverted to R4's proven dispatch structure, keeping only the
// two audited wins:
//  (1) scatter block 0 persists binbase[393] (it computes the scan anyway);
//  (2) nodesort reads binbase (8B) + stages its bin's recs in LDS (8KB) ->
//      kills R4's 392x150KB hist re-read (59MB logical) + per-block scan.
//  D1 hist:     96 blocks, LDS hist over 392 bins (+ fused wcvt in blk 0,1).
//  D2 scatter:  self-scan -> bases, LDS tickets -> recs=(dst16|src16),
//               blk0 persists binbase.
//  D3 gemm:     Y = feat @ W, bf16 MFMA (verified 16-row tile, 3125 blocks).
//  D4 nodesort: 392 blocks; LDS-staged per-bin 128-node count/scan/scatter ->
//               exact CSR (nodeoff[50177], edst u16).
//  D5 gather:   1 wave/node on exact CSR, uint4 row loads, shfl reduce.
// Workspace: Y 12.8MB | Wf 32KB | hist 150KB | binbase 1.6KB | nodeoff 201KB
//            | recs 2.56MB | edst 1.28MB (~17MB).
// ---------------------------------------------------------------------------

typedef __attribute__((ext_vector_type(8))) short short8;   // 8 bf16 (4 VGPRs)
typedef __attribute__((ext_vector_type(4))) float f32x4;    // MFMA C/D

static __device__ inline unsigned pkbf(float lo, float hi) {
    unsigned a = __float_as_uint(lo) + 0x8000u;
    unsigned b = __float_as_uint(hi) + 0x8000u;
    return __builtin_amdgcn_perm(b, a, 0x07060302);
}
static __device__ inline unsigned short f2bf(float f) {
    return (unsigned short)((__float_as_uint(f) + 0x8000u) >> 16);
}
static __device__ inline float bflo(unsigned u) { return __uint_as_float(u << 16); }
static __device__ inline float bfhi(unsigned u) { return __uint_as_float(u & 0xFFFF0000u); }

// D1: per-chunk histogram over bins (LDS atomics, int4 edge stream) + wcvt.
__global__ __launch_bounds__(1024) void hist_kernel(
        const int4* __restrict__ dst4,
        const float* __restrict__ W,
        uint4* __restrict__ Wf,
        unsigned* __restrict__ hist) {
    __shared__ unsigned h[NBINS];
    const int t = threadIdx.x;
    const int blk = blockIdx.x;
    if (t < NBINS) h[t] = 0;

    if (blk < 2) {                                   // fused wcvt: e = 0..2047
        int e = blk * 1024 + t;
        int q  = e & 3;
        int n  = (e >> 2) & 15;
        int nt = (e >> 6) & 7;
        int kt = e >> 9;
        const float* p = W + (kt * 32 + q * 8) * D + nt * 16 + n;
        unsigned u[8];
        #pragma unroll
        for (int j = 0; j < 8; ++j) u[j] = __float_as_uint(p[j * D]) + 0x8000u;
        uint4 o;
        o.x = __builtin_amdgcn_perm(u[1], u[0], 0x07060302);
        o.y = __builtin_amdgcn_perm(u[3], u[2], 0x07060302);
        o.z = __builtin_amdgcn_perm(u[5], u[4], 0x07060302);
        o.w = __builtin_amdgcn_perm(u[7], u[6], 0x07060302);
        Wf[e] = o;
    }
    __syncthreads();

    const int i0 = blk * EPC4;
    const int i1 = min(i0 + EPC4, NQUADS);
    for (int i = i0 + t; i < i1; i += 1024) {
        int4 d = dst4[i];
        atomicAdd(&h[((unsigned)d.x) >> 7], 1u);
        atomicAdd(&h[((unsigned)d.y) >> 7], 1u);
        atomicAdd(&h[((unsigned)d.z) >> 7], 1u);
        atomicAdd(&h[((unsigned)d.w) >> 7], 1u);
    }
    __syncthreads();
    if (t < NBINS) hist[blk * NBINS + t] = h[t];     // coalesced
}

// D2: scatter with self-computed global bases; block 0 persists binbase.
__global__ __launch_bounds__(1024) void scatter_kernel(
        const int4* __restrict__ src4,
        const int4* __restrict__ dst4,
        const unsigned* __restrict__ hist,
        unsigned* __restrict__ recs,
        unsigned* __restrict__ binbase) {
    __shared__ unsigned sc[512];
    __shared__ unsigned lb[NBINS];
    __shared__ unsigned h[NBINS];
    const int t = threadIdx.x;
    const int blk = blockIdx.x;

    unsigned pre = 0, tot = 0;                       // per-bin t: prefix & total
    if (t < NBINS)
        for (int k = 0; k < NCHUNK; ++k) {
            unsigned v = hist[k * NBINS + t];
            if (k < blk) pre += v;
            tot += v;
        }
    if (t < 512) sc[t] = (t < NBINS) ? tot : 0;
    __syncthreads();
    for (int off = 1; off < 512; off <<= 1) {        // inclusive scan over bins
        unsigned v = 0;
        if (t < 512) { v = sc[t]; if (t >= off) v += sc[t - off]; }
        __syncthreads();
        if (t < 512) sc[t] = v;
        __syncthreads();
    }
    if (t < NBINS) {
        unsigned bbs = (t == 0) ? 0u : sc[t - 1];    // exclusive bin base
        lb[t] = bbs + pre;                           // this block's write base
        h[t] = 0;
        if (blk == 0) binbase[t] = bbs;              // persist for nodesort
    }
    if (blk == 0 && t == NBINS) binbase[NBINS] = N_EDGES;
    __syncthreads();

    const int i0 = blk * EPC4;
    const int i1 = min(i0 + EPC4, NQUADS);
    for (int i = i0 + t; i < i1; i += 1024) {
        int4 s = src4[i];
        int4 d = dst4[i];
        #pragma unroll
        for (int u = 0; u < 4; ++u) {
            int dd = (u == 0) ? d.x : (u == 1) ? d.y : (u == 2) ? d.z : d.w;
            int ss = (u == 0) ? s.x : (u == 1) ? s.y : (u == 2) ? s.z : s.w;
            unsigned bin = ((unsigned)dd) >> 7;
            unsigned r = atomicAdd(&h[bin], 1u);     // LDS ticket
            unsigned off = lb[bin] + r;
            if (off < N_EDGES)                       // exact; safety guard
                recs[off] = (((unsigned)dd) << 16) | (unsigned)ss;
        }
    }
}

// D3: pure gemm tile (16 rows/block). A-frag: lane(n,q) holds A[m=n][k=q*8+j];
// C/D: col=n, row=q*4+reg. B-frags: 8 coalesced uint4/lane from Wf.
__global__ __launch_bounds__(256) void gemm_kernel(
        const uint4* __restrict__ Wf,
        const float* __restrict__ feat,
        unsigned short* __restrict__ Y) {
    const int t = threadIdx.x;
    const int tile = blockIdx.x;                     // 0..3124
    const int wave = t >> 6;
    const int lane = t & 63;
    const int n = lane & 15;
    const int q = lane >> 4;

    short8 bfrag[4][2];
    #pragma unroll
    for (int kt = 0; kt < 4; ++kt) {
        #pragma unroll
        for (int p = 0; p < 2; ++p) {
            int nt = wave * 2 + p;
            uint4 raw = Wf[(((kt * 8 + nt) * 16 + n) << 2) + q];
            bfrag[kt][p] = *(const short8*)&raw;
        }
    }

    const float* ap = feat + (size_t)(tile * 16 + n) * D + q * 8;
    f32x4 acc0 = {0.f, 0.f, 0.f, 0.f};
    f32x4 acc1 = {0.f, 0.f, 0.f, 0.f};
    #pragma unroll
    for (int kt = 0; kt < 4; ++kt) {
        float4 f0 = *(const float4*)(ap + kt * 32);
        float4 f1 = *(const float4*)(ap + kt * 32 + 4);
        int4 pa;
        pa.x = (int)pkbf(f0.x, f0.y);
        pa.y = (int)pkbf(f0.z, f0.w);
        pa.z = (int)pkbf(f1.x, f1.y);
        pa.w = (int)pkbf(f1.z, f1.w);
        short8 afrag = *(const short8*)&pa;
        acc0 = __builtin_amdgcn_mfma_f32_16x16x32_bf16(afrag, bfrag[kt][0], acc0, 0, 0, 0);
        acc1 = __builtin_amdgcn_mfma_f32_16x16x32_bf16(afrag, bfrag[kt][1], acc1, 0, 0, 0);
    }
    unsigned short* yp = Y + (size_t)(tile * 16 + q * 4) * D + n;
    #pragma unroll
    for (int i = 0; i < 4; ++i) {
        yp[(size_t)i * D + wave * 32]      = f2bf(acc0[i]);
        yp[(size_t)i * D + wave * 32 + 16] = f2bf(acc1[i]);
    }
}

// D4: per-bin node sort -> exact CSR. Reads binbase (8B); LDS-staged records,
// single global pass over recs.
__global__ __launch_bounds__(512) void nodesort_kernel(
        const unsigned* __restrict__ binbase,
        const unsigned* __restrict__ recs,
        unsigned* __restrict__ nodeoff,
        unsigned short* __restrict__ edst) {
    __shared__ unsigned lrec[BINCAP];        // 8 KB staged records
    __shared__ unsigned cnt128[128];
    __shared__ unsigned ns[129];
    __shared__ unsigned tick[128];
    const int t = threadIdx.x;
    const int b = blockIdx.x;
    const unsigned s0 = binbase[b];
    const unsigned e1 = binbase[b + 1];
    unsigned n = e1 - s0;
    if (n > BINCAP) n = BINCAP;              // statistically impossible; safety
    if (t < 128) cnt128[t] = 0;
    __syncthreads();
    for (unsigned i = t; i < n; i += 512) {
        unsigned r = recs[s0 + i];
        lrec[i] = r;
        atomicAdd(&cnt128[(r >> 16) & 127u], 1u);
    }
    __syncthreads();
    if (t == 0) {
        unsigned a = 0;
        for (int i = 0; i < 128; ++i) { ns[i] = a; a += cnt128[i]; }
        ns[128] = a;
    }
    __syncthreads();
    if (t < 128) {
        tick[t] = ns[t];
        nodeoff[b * 128 + t] = s0 + ns[t];
    }
    if (b == 0 && t == 128) nodeoff[NBINS * 128] = N_EDGES;
    __syncthreads();
    for (unsigned i = t; i < n; i += 512) {
        unsigned r = lrec[i];
        unsigned off = s0 + atomicAdd(&tick[(r >> 16) & 127u], 1u);
        edst[off] = (unsigned short)(r & 0xFFFFu);
    }
}

#define ACC8(v)                                              \
    do {                                                     \
        ax[0] += bflo((v).x); ax[1] += bfhi((v).x);          \
        ax[2] += bflo((v).y); ax[3] += bfhi((v).y);          \
        ax[4] += bflo((v).z); ax[5] += bfhi((v).z);          \
        ax[6] += bflo((v).w); ax[7] += bfhi((v).w);          \
    } while (0)

// D5: gather on exact CSR. One wave per node (50K waves). Guard-free main
// loop (j+8<=m) with two 1KB row-loads in flight; single; masked tail.
__global__ __launch_bounds__(256) void gather_kernel(
        const uint4* __restrict__ Y4,        // [N][16] uint4 (row = 256B)
        const unsigned* __restrict__ nodeoff,
        const unsigned short* __restrict__ edst,
        const float4* __restrict__ b4,       // [32] float4
        float* __restrict__ out) {
    int node = (blockIdx.x * 256 + threadIdx.x) >> 6;
    int lane = threadIdx.x & 63;
    if (node >= N_NODES) return;
    unsigned start = nodeoff[node];
    int cnt = (int)(nodeoff[node + 1] - start);      // exact degree
    const int q = lane >> 4;
    const int c = lane & 15;

    float ax[8];
    #pragma unroll
    for (int i = 0; i < 8; ++i) ax[i] = 0.f;

    for (int c0 = 0; c0 < cnt; c0 += 64) {           // deg>64 handled exactly
        int m = min(cnt - c0, 64);
        int eid = (lane < m) ? (int)edst[start + c0 + lane] : 0;
        int j = 0;
        for (; j + 8 <= m; j += 8) {                 // 2 loads in flight
            int sA = __shfl(eid, j + q);
            int sB = __shfl(eid, j + 4 + q);
            uint4 vA = Y4[(size_t)sA * 16 + c];
            uint4 vB = Y4[(size_t)sB * 16 + c];
            ACC8(vA);
            ACC8(vB);
        }
        for (; j + 4 <= m; j += 4) {                 // guard-free single
            int s = __shfl(eid, j + q);
            uint4 v = Y4[(size_t)s * 16 + c];
            ACC8(v);
        }
        if (j < m) {                                 // masked tail (<=3 rows)
            int idx = j + q;
            int s = __shfl(eid, (idx < m) ? idx : 0);
            uint4 v = make_uint4(0u, 0u, 0u, 0u);
            if (idx < m) v = Y4[(size_t)s * 16 + c];
            ACC8(v);
        }
    }

    #pragma unroll
    for (int i = 0; i < 8; ++i) {
        ax[i] += __shfl_xor(ax[i], 16);
        ax[i] += __shfl_xor(ax[i], 32);              // all lanes hold full sums
    }

    if (lane < 32) {
        int q2 = lane >> 4;                          // 0: cols c*8+0..3, 1: +4..7
        float4 bb = b4[c * 2 + q2];
        float4 o;
        o.x = ax[q2 * 4 + 0] + bb.x;
        o.y = ax[q2 * 4 + 1] + bb.y;
        o.z = ax[q2 * 4 + 2] + bb.z;
        o.w = ax[q2 * 4 + 3] + bb.w;
        *(float4*)(out + (size_t)node * D + c * 8 + q2 * 4) = o;
    }
}

// ---------------------------------------------------------------------------
extern "C" void kernel_launch(void* const* d_in, const int* in_sizes, int n_in,
                              void* d_out, int out_size, void* d_ws, size_t ws_size,
                              hipStream_t stream) {
    const float* feat = (const float*)d_in[0];   // [50000,128] f32
    const int*   src  = (const int*)d_in[1];     // [640000] int32
    const int*   dst  = (const int*)d_in[2];     // [640000] int32
    const float* W    = (const float*)d_in[3];   // [128,128] f32
    const float* b    = (const float*)d_in[4];   // [1,128]   f32
    float* out = (float*)d_out;                  // [50000,128] f32

    unsigned short* Y = (unsigned short*)d_ws;                        // 12.8 MB
    uint4* Wf = (uint4*)((char*)d_ws + (size_t)N_NODES * D * 2);      // 32 KB
    unsigned* hist    = (unsigned*)((char*)Wf + 2048 * sizeof(uint4));// 150 KB
    unsigned* binbase = hist + NCHUNK * NBINS;                        // 1.6 KB
    unsigned* nodeoff = binbase + (NBINS + 1);                        // 201 KB
    unsigned* recs    = nodeoff + (NBINS * 128 + 1);                  // 2.56 MB
    unsigned short* edst = (unsigned short*)(recs + N_EDGES);         // 1.28 MB

    hist_kernel<<<NCHUNK, 1024, 0, stream>>>((const int4*)dst, W, Wf, hist);
    scatter_kernel<<<NCHUNK, 1024, 0, stream>>>(
        (const int4*)src, (const int4*)dst, hist, recs, binbase);
    gemm_kernel<<<3125, 256, 0, stream>>>(Wf, feat, Y);
    nodesort_kernel<<<NBINS, 512, 0, stream>>>(binbase, recs, nodeoff, edst);
    gather_kernel<<<N_NODES * 64 / 256, 256, 0, stream>>>(
        (const uint4*)Y, nodeoff, edst, (const float4*)b, out);
}

// Round 7
// 145.319 us; speedup vs baseline: 4.5272x; 1.0097x over previous
//
#include <hip/hip_runtime.h>

#define N_NODES 50000
#define N_EDGES 640000
#define D 128               // D_IN == D_OUT == 128
#define NBINS 392           // bin = dst>>7 (128 nodes/bin); 392*128 = 50176 >= N
#define NCHUNK 96           // fat edge chunks for hist/scatter
#define NQUADS 160000       // N_EDGES/4 (int4 granularity; 640000 % 4 == 0)
#define EPC4 1667            // int4 quads per chunk: 96*1667 = 160032 >= 160000
#define BINCAP 2048         // LDS staging cap in nodesort (mean 1638, +10σ)

// ---------------------------------------------------------------------------
// 5-dispatch, zero-global-atomic pipeline (R6 structure, verified 146.7us).
// R7: gather is the dominant own-kernel (~25us vs ~12us roofline), and it is
// LATENCY-bound: mean deg 12.8 -> the 2-deep loop serializes 3 dependent
// memory round-trips per wave. Fix: branch-free masked 16-row groups -> 4
// uint4 loads ALWAYS in flight (invalid rows read row 0, zeroed by cndmask).
// 79% of nodes (deg<=16) collapse to ONE round-trip.
//  D1 hist:     96 blocks, LDS hist over 392 bins (+ fused wcvt in blk 0,1).
//  D2 scatter:  self-scan -> bases, LDS tickets -> recs=(dst16|src16),
//               blk0 persists binbase.
//  D3 gemm:     Y = feat @ W, bf16 MFMA (verified 16-row tile, 3125 blocks).
//  D4 nodesort: 392 blocks; LDS-staged per-bin 128-node count/scan/scatter ->
//               exact CSR (nodeoff[50177], edst u16).
//  D5 gather:   1 wave/node on exact CSR, masked 4-deep uint4 row loads,
//               shfl reduce.
// Workspace: Y 12.8MB | Wf 32KB | hist 150KB | binbase 1.6KB | nodeoff 201KB
//            | recs 2.56MB | edst 1.28MB (~17MB).
// ---------------------------------------------------------------------------

typedef __attribute__((ext_vector_type(8))) short short8;   // 8 bf16 (4 VGPRs)
typedef __attribute__((ext_vector_type(4))) float f32x4;    // MFMA C/D

static __device__ inline unsigned pkbf(float lo, float hi) {
    unsigned a = __float_as_uint(lo) + 0x8000u;
    unsigned b = __float_as_uint(hi) + 0x8000u;
    return __builtin_amdgcn_perm(b, a, 0x07060302);
}
static __device__ inline unsigned short f2bf(float f) {
    return (unsigned short)((__float_as_uint(f) + 0x8000u) >> 16);
}
static __device__ inline float bflo(unsigned u) { return __uint_as_float(u << 16); }
static __device__ inline float bfhi(unsigned u) { return __uint_as_float(u & 0xFFFF0000u); }

// D1: per-chunk histogram over bins (LDS atomics, int4 edge stream) + wcvt.
__global__ __launch_bounds__(1024) void hist_kernel(
        const int4* __restrict__ dst4,
        const float* __restrict__ W,
        uint4* __restrict__ Wf,
        unsigned* __restrict__ hist) {
    __shared__ unsigned h[NBINS];
    const int t = threadIdx.x;
    const int blk = blockIdx.x;
    if (t < NBINS) h[t] = 0;

    if (blk < 2) {                                   // fused wcvt: e = 0..2047
        int e = blk * 1024 + t;
        int q  = e & 3;
        int n  = (e >> 2) & 15;
        int nt = (e >> 6) & 7;
        int kt = e >> 9;
        const float* p = W + (kt * 32 + q * 8) * D + nt * 16 + n;
        unsigned u[8];
        #pragma unroll
        for (int j = 0; j < 8; ++j) u[j] = __float_as_uint(p[j * D]) + 0x8000u;
        uint4 o;
        o.x = __builtin_amdgcn_perm(u[1], u[0], 0x07060302);
        o.y = __builtin_amdgcn_perm(u[3], u[2], 0x07060302);
        o.z = __builtin_amdgcn_perm(u[5], u[4], 0x07060302);
        o.w = __builtin_amdgcn_perm(u[7], u[6], 0x07060302);
        Wf[e] = o;
    }
    __syncthreads();

    const int i0 = blk * EPC4;
    const int i1 = min(i0 + EPC4, NQUADS);
    for (int i = i0 + t; i < i1; i += 1024) {
        int4 d = dst4[i];
        atomicAdd(&h[((unsigned)d.x) >> 7], 1u);
        atomicAdd(&h[((unsigned)d.y) >> 7], 1u);
        atomicAdd(&h[((unsigned)d.z) >> 7], 1u);
        atomicAdd(&h[((unsigned)d.w) >> 7], 1u);
    }
    __syncthreads();
    if (t < NBINS) hist[blk * NBINS + t] = h[t];     // coalesced
}

// D2: scatter with self-computed global bases; block 0 persists binbase.
__global__ __launch_bounds__(1024) void scatter_kernel(
        const int4* __restrict__ src4,
        const int4* __restrict__ dst4,
        const unsigned* __restrict__ hist,
        unsigned* __restrict__ recs,
        unsigned* __restrict__ binbase) {
    __shared__ unsigned sc[512];
    __shared__ unsigned lb[NBINS];
    __shared__ unsigned h[NBINS];
    const int t = threadIdx.x;
    const int blk = blockIdx.x;

    unsigned pre = 0, tot = 0;                       // per-bin t: prefix & total
    if (t < NBINS)
        for (int k = 0; k < NCHUNK; ++k) {
            unsigned v = hist[k * NBINS + t];
            if (k < blk) pre += v;
            tot += v;
        }
    if (t < 512) sc[t] = (t < NBINS) ? tot : 0;
    __syncthreads();
    for (int off = 1; off < 512; off <<= 1) {        // inclusive scan over bins
        unsigned v = 0;
        if (t < 512) { v = sc[t]; if (t >= off) v += sc[t - off]; }
        __syncthreads();
        if (t < 512) sc[t] = v;
        __syncthreads();
    }
    if (t < NBINS) {
        unsigned bbs = (t == 0) ? 0u : sc[t - 1];    // exclusive bin base
        lb[t] = bbs + pre;                           // this block's write base
        h[t] = 0;
        if (blk == 0) binbase[t] = bbs;              // persist for nodesort
    }
    if (blk == 0 && t == NBINS) binbase[NBINS] = N_EDGES;
    __syncthreads();

    const int i0 = blk * EPC4;
    const int i1 = min(i0 + EPC4, NQUADS);
    for (int i = i0 + t; i < i1; i += 1024) {
        int4 s = src4[i];
        int4 d = dst4[i];
        #pragma unroll
        for (int u = 0; u < 4; ++u) {
            int dd = (u == 0) ? d.x : (u == 1) ? d.y : (u == 2) ? d.z : d.w;
            int ss = (u == 0) ? s.x : (u == 1) ? s.y : (u == 2) ? s.z : s.w;
            unsigned bin = ((unsigned)dd) >> 7;
            unsigned r = atomicAdd(&h[bin], 1u);     // LDS ticket
            unsigned off = lb[bin] + r;
            if (off < N_EDGES)                       // exact; safety guard
                recs[off] = (((unsigned)dd) << 16) | (unsigned)ss;
        }
    }
}

// D3: pure gemm tile (16 rows/block). A-frag: lane(n,q) holds A[m=n][k=q*8+j];
// C/D: col=n, row=q*4+reg. B-frags: 8 coalesced uint4/lane from Wf.
__global__ __launch_bounds__(256) void gemm_kernel(
        const uint4* __restrict__ Wf,
        const float* __restrict__ feat,
        unsigned short* __restrict__ Y) {
    const int t = threadIdx.x;
    const int tile = blockIdx.x;                     // 0..3124
    const int wave = t >> 6;
    const int lane = t & 63;
    const int n = lane & 15;
    const int q = lane >> 4;

    short8 bfrag[4][2];
    #pragma unroll
    for (int kt = 0; kt < 4; ++kt) {
        #pragma unroll
        for (int p = 0; p < 2; ++p) {
            int nt = wave * 2 + p;
            uint4 raw = Wf[(((kt * 8 + nt) * 16 + n) << 2) + q];
            bfrag[kt][p] = *(const short8*)&raw;
        }
    }

    const float* ap = feat + (size_t)(tile * 16 + n) * D + q * 8;
    f32x4 acc0 = {0.f, 0.f, 0.f, 0.f};
    f32x4 acc1 = {0.f, 0.f, 0.f, 0.f};
    #pragma unroll
    for (int kt = 0; kt < 4; ++kt) {
        float4 f0 = *(const float4*)(ap + kt * 32);
        float4 f1 = *(const float4*)(ap + kt * 32 + 4);
        int4 pa;
        pa.x = (int)pkbf(f0.x, f0.y);
        pa.y = (int)pkbf(f0.z, f0.w);
        pa.z = (int)pkbf(f1.x, f1.y);
        pa.w = (int)pkbf(f1.z, f1.w);
        short8 afrag = *(const short8*)&pa;
        acc0 = __builtin_amdgcn_mfma_f32_16x16x32_bf16(afrag, bfrag[kt][0], acc0, 0, 0, 0);
        acc1 = __builtin_amdgcn_mfma_f32_16x16x32_bf16(afrag, bfrag[kt][1], acc1, 0, 0, 0);
    }
    unsigned short* yp = Y + (size_t)(tile * 16 + q * 4) * D + n;
    #pragma unroll
    for (int i = 0; i < 4; ++i) {
        yp[(size_t)i * D + wave * 32]      = f2bf(acc0[i]);
        yp[(size_t)i * D + wave * 32 + 16] = f2bf(acc1[i]);
    }
}

// D4: per-bin node sort -> exact CSR. Reads binbase (8B); LDS-staged records,
// single global pass over recs.
__global__ __launch_bounds__(512) void nodesort_kernel(
        const unsigned* __restrict__ binbase,
        const unsigned* __restrict__ recs,
        unsigned* __restrict__ nodeoff,
        unsigned short* __restrict__ edst) {
    __shared__ unsigned lrec[BINCAP];        // 8 KB staged records
    __shared__ unsigned cnt128[128];
    __shared__ unsigned ns[129];
    __shared__ unsigned tick[128];
    const int t = threadIdx.x;
    const int b = blockIdx.x;
    const unsigned s0 = binbase[b];
    const unsigned e1 = binbase[b + 1];
    unsigned n = e1 - s0;
    if (n > BINCAP) n = BINCAP;              // statistically impossible; safety
    if (t < 128) cnt128[t] = 0;
    __syncthreads();
    for (unsigned i = t; i < n; i += 512) {
        unsigned r = recs[s0 + i];
        lrec[i] = r;
        atomicAdd(&cnt128[(r >> 16) & 127u], 1u);
    }
    __syncthreads();
    if (t == 0) {
        unsigned a = 0;
        for (int i = 0; i < 128; ++i) { ns[i] = a; a += cnt128[i]; }
        ns[128] = a;
    }
    __syncthreads();
    if (t < 128) {
        tick[t] = ns[t];
        nodeoff[b * 128 + t] = s0 + ns[t];
    }
    if (b == 0 && t == 128) nodeoff[NBINS * 128] = N_EDGES;
    __syncthreads();
    for (unsigned i = t; i < n; i += 512) {
        unsigned r = lrec[i];
        unsigned off = s0 + atomicAdd(&tick[(r >> 16) & 127u], 1u);
        edst[off] = (unsigned short)(r & 0xFFFFu);
    }
}

#define ACC8(v)                                              \
    do {                                                     \
        ax[0] += bflo((v).x); ax[1] += bfhi((v).x);          \
        ax[2] += bflo((v).y); ax[3] += bfhi((v).y);          \
        ax[4] += bflo((v).z); ax[5] += bfhi((v).z);          \
        ax[6] += bflo((v).w); ax[7] += bfhi((v).w);          \
    } while (0)

// D5: gather on exact CSR. One wave per node (50K waves). Branch-free masked
// 16-row groups: 4 uint4 loads ALWAYS in flight; invalid rows read row 0
// (eid pre-zeroed for lanes >= m) and are zeroed via cndmask before ACC8.
// deg<=16 nodes (79%) = ONE memory round-trip instead of three.
__global__ __launch_bounds__(256) void gather_kernel(
        const uint4* __restrict__ Y4,        // [N][16] uint4 (row = 256B)
        const unsigned* __restrict__ nodeoff,
        const unsigned short* __restrict__ edst,
        const float4* __restrict__ b4,       // [32] float4
        float* __restrict__ out) {
    int node = (blockIdx.x * 256 + threadIdx.x) >> 6;
    int lane = threadIdx.x & 63;
    if (node >= N_NODES) return;
    unsigned start = nodeoff[node];
    int cnt = (int)(nodeoff[node + 1] - start);      // exact degree
    const int q = lane >> 4;
    const int c = lane & 15;

    float ax[8];
    #pragma unroll
    for (int i = 0; i < 8; ++i) ax[i] = 0.f;

    for (int c0 = 0; c0 < cnt; c0 += 64) {           // deg>64 handled exactly
        int m = min(cnt - c0, 64);
        int eid = (lane < m) ? (int)edst[start + c0 + lane] : 0;
        for (int j = 0; j < m; j += 16) {            // masked 16-row groups
            int i0 = j + q, i1 = j + 4 + q, i2 = j + 8 + q, i3 = j + 12 + q;
            int s0 = __shfl(eid, i0 & 63);           // lanes >= m hold eid=0
            int s1 = __shfl(eid, i1 & 63);
            int s2 = __shfl(eid, i2 & 63);
            int s3 = __shfl(eid, i3 & 63);
            uint4 v0 = Y4[(size_t)s0 * 16 + c];      // 4 loads in flight
            uint4 v1 = Y4[(size_t)s1 * 16 + c];
            uint4 v2 = Y4[(size_t)s2 * 16 + c];
            uint4 v3 = Y4[(size_t)s3 * 16 + c];
            v0.x = (i0 < m) ? v0.x : 0u; v0.y = (i0 < m) ? v0.y : 0u;
            v0.z = (i0 < m) ? v0.z : 0u; v0.w = (i0 < m) ? v0.w : 0u;
            v1.x = (i1 < m) ? v1.x : 0u; v1.y = (i1 < m) ? v1.y : 0u;
            v1.z = (i1 < m) ? v1.z : 0u; v1.w = (i1 < m) ? v1.w : 0u;
            v2.x = (i2 < m) ? v2.x : 0u; v2.y = (i2 < m) ? v2.y : 0u;
            v2.z = (i2 < m) ? v2.z : 0u; v2.w = (i2 < m) ? v2.w : 0u;
            v3.x = (i3 < m) ? v3.x : 0u; v3.y = (i3 < m) ? v3.y : 0u;
            v3.z = (i3 < m) ? v3.z : 0u; v3.w = (i3 < m) ? v3.w : 0u;
            ACC8(v0);
            ACC8(v1);
            ACC8(v2);
            ACC8(v3);
        }
    }

    #pragma unroll
    for (int i = 0; i < 8; ++i) {
        ax[i] += __shfl_xor(ax[i], 16);
        ax[i] += __shfl_xor(ax[i], 32);              // all lanes hold full sums
    }

    if (lane < 32) {
        int q2 = lane >> 4;                          // 0: cols c*8+0..3, 1: +4..7
        float4 bb = b4[c * 2 + q2];
        float4 o;
        o.x = ax[q2 * 4 + 0] + bb.x;
        o.y = ax[q2 * 4 + 1] + bb.y;
        o.z = ax[q2 * 4 + 2] + bb.z;
        o.w = ax[q2 * 4 + 3] + bb.w;
        *(float4*)(out + (size_t)node * D + c * 8 + q2 * 4) = o;
    }
}

// ---------------------------------------------------------------------------
extern "C" void kernel_launch(void* const* d_in, const int* in_sizes, int n_in,
                              void* d_out, int out_size, void* d_ws, size_t ws_size,
                              hipStream_t stream) {
    const float* feat = (const float*)d_in[0];   // [50000,128] f32
    const int*   src  = (const int*)d_in[1];     // [640000] int32
    const int*   dst  = (const int*)d_in[2];     // [640000] int32
    const float* W    = (const float*)d_in[3];   // [128,128] f32
    const float* b    = (const float*)d_in[4];   // [1,128]   f32
    float* out = (float*)d_out;                  // [50000,128] f32

    unsigned short* Y = (unsigned short*)d_ws;                        // 12.8 MB
    uint4* Wf = (uint4*)((char*)d_ws + (size_t)N_NODES * D * 2);      // 32 KB
    unsigned* hist    = (unsigned*)((char*)Wf + 2048 * sizeof(uint4));// 150 KB
    unsigned* binbase = hist + NCHUNK * NBINS;                        // 1.6 KB
    unsigned* nodeoff = binbase + (NBINS + 1);                        // 201 KB
    unsigned* recs    = nodeoff + (NBINS * 128 + 1);                  // 2.56 MB
    unsigned short* edst = (unsigned short*)(recs + N_EDGES);         // 1.28 MB

    hist_kernel<<<NCHUNK, 1024, 0, stream>>>((const int4*)dst, W, Wf, hist);
    scatter_kernel<<<NCHUNK, 1024, 0, stream>>>(
        (const int4*)src, (const int4*)dst, hist, recs, binbase);
    gemm_kernel<<<3125, 256, 0, stream>>>(Wf, feat, Y);
    nodesort_kernel<<<NBINS, 512, 0, stream>>>(binbase, recs, nodeoff, edst);
    gather_kernel<<<N_NODES * 64 / 256, 256, 0, stream>>>(
        (const uint4*)Y, nodeoff, edst, (const float4*)b, out);
}